// Round 5
// baseline (160.732 us; speedup 1.0000x reference)
//
#include <hip/hip_runtime.h>
#include <stdint.h>
#include <math.h>

// SparseBox3DDecoderLite: B=8, Q=100000, C=10, K=1000
// Single 32MB pass: fused hist + speculative candidate staging (bin>=3075,
// i.e. logit>=2.75) -> exact threshold from summed private hists + compact
// spec list -> (repair rescan if speculation failed; never on this data) ->
// wide rank-count select -> wide rerank sort + decode.
// Outputs (float32, concatenated): boxes[8,1000,10], final_scores[8,1000],
// labels[8,1000], raw_scores[8,1000]  => 104000 floats.

#define BATCHES 8
#define NQ 100000
#define NEL 1000000   // Q*C per batch
#define NVEC 250000   // NEL/4
#define TOPK 1000
#define NBINS 4096
#define CAP 2048
#define NBLK_H 32     // blocks per batch, histspec/repair
#define STAGE_CAP 512
#define SPEC_CAP 8192
#define SPEC_BIN 3075u   // f2key(2.75f)>>20; exact tb is 3076 (logit>=3.0, n~1350)
#define SELBLK 16     // blocks per batch, select (16*128 == CAP)
#define SELTHR 128
#define SRTBLK 16     // blocks per batch, sortdecode (16*64 >= TOPK)

__device__ __forceinline__ unsigned f2key(float f) {
    unsigned b = __float_as_uint(f);
    return b ^ ((b & 0x80000000u) ? 0xFFFFFFFFu : 0x80000000u);
}
__device__ __forceinline__ float key2f(unsigned k) {
    unsigned b = (k & 0x80000000u) ? (k ^ 0x80000000u) : ~k;
    return __uint_as_float(b);
}

// One 32MB pass: private LDS histogram (written to ws, no atomics) +
// speculative staging of all elements with bin >= SPEC_BIN.
__global__ __launch_bounds__(512) void histspec_kernel(const float* __restrict__ cls,
                                                       unsigned* __restrict__ phist,
                                                       unsigned* __restrict__ speccnt,
                                                       unsigned long long* __restrict__ spec) {
    __shared__ unsigned lh[NBINS];
    __shared__ unsigned long long stg[STAGE_CAP];
    __shared__ unsigned lcnt, gbase;
    const int b = blockIdx.x / NBLK_H;
    const int blk = blockIdx.x % NBLK_H;
    for (int i = threadIdx.x; i < NBINS; i += 512) lh[i] = 0;
    if (threadIdx.x == 0) lcnt = 0;
    __syncthreads();
    const float4* src = (const float4*)(cls + (size_t)b * NEL);
    unsigned long long* sb = spec + (size_t)b * SPEC_CAP;
    for (int i = blk * 512 + threadIdx.x; i < NVEC; i += NBLK_H * 512) {
        float4 v = src[i];
        float xs[4] = {v.x, v.y, v.z, v.w};
#pragma unroll
        for (int j = 0; j < 4; ++j) {
            unsigned k = f2key(xs[j]);
            atomicAdd(&lh[k >> 20], 1u);
            if ((k >> 20) >= SPEC_BIN) {
                unsigned long long pack = ((unsigned long long)k << 32) |
                                          (unsigned long long)(0xFFFFFFFFu - (unsigned)(i * 4 + j));
                unsigned p = atomicAdd(&lcnt, 1u);
                if (p < STAGE_CAP) stg[p] = pack;
                else {  // exactness fallback (never: ~93 spec/block expected)
                    unsigned pos = atomicAdd(&speccnt[b], 1u);
                    if (pos < SPEC_CAP) sb[pos] = pack;
                }
            }
        }
    }
    __syncthreads();
    // private hist -> global ws, coalesced uint4, no atomics
    uint4* ph = (uint4*)(phist + ((size_t)b * NBLK_H + blk) * NBINS);
    for (int i = threadIdx.x; i < NBINS / 4; i += 512) ph[i] = ((uint4*)lh)[i];
    unsigned n = lcnt < STAGE_CAP ? lcnt : STAGE_CAP;
    if (threadIdx.x == 0) gbase = atomicAdd(&speccnt[b], n);
    __syncthreads();
    for (unsigned t = threadIdx.x; t < n; t += 512) {
        unsigned pos = gbase + t;
        if (pos < SPEC_CAP) sb[pos] = stg[t];
    }
}

// Per batch: sum 32 private hists, find exact threshold bin, compact the
// spec list into cand (one block per batch -> LDS counter, no contention).
__global__ __launch_bounds__(256) void threshcompact_kernel(const unsigned* __restrict__ phist,
                                                            const unsigned* __restrict__ speccnt,
                                                            const unsigned long long* __restrict__ spec,
                                                            unsigned* __restrict__ tbin,
                                                            unsigned* __restrict__ cnt,
                                                            unsigned long long* __restrict__ cand,
                                                            unsigned* __restrict__ flag) {
    __shared__ unsigned sh[NBINS];
    __shared__ unsigned coarse[256];
    __shared__ unsigned stb, lcnt;
    const int b = blockIdx.x;
    const int tid = threadIdx.x;
    unsigned sum[16];
#pragma unroll
    for (int j = 0; j < 16; ++j) sum[j] = 0;
    const unsigned* ph = phist + (size_t)b * NBLK_H * NBINS;
    for (int h = 0; h < NBLK_H; ++h) {
        const uint4* p4 = (const uint4*)(ph + h * NBINS + tid * 16);
#pragma unroll
        for (int g = 0; g < 4; ++g) {
            uint4 v = p4[g];
            sum[g * 4 + 0] += v.x; sum[g * 4 + 1] += v.y;
            sum[g * 4 + 2] += v.z; sum[g * 4 + 3] += v.w;
        }
    }
    unsigned csum = 0;
#pragma unroll
    for (int j = 0; j < 16; ++j) { sh[tid * 16 + j] = sum[j]; csum += sum[j]; }
    coarse[tid] = csum;
    if (tid == 0) lcnt = 0;
    __syncthreads();
    if (tid == 0) {
        unsigned acc = 0;
        int tb = 0;
        for (int c = 255; c >= 0; --c) {
            if (acc + coarse[c] >= (unsigned)TOPK) {
                for (int bin = c * 16 + 15; bin >= c * 16; --bin) {
                    acc += sh[bin];
                    if (acc >= (unsigned)TOPK) { tb = bin; break; }
                }
                break;
            }
            acc += coarse[c];
        }
        tbin[b] = (unsigned)tb;
        stb = (unsigned)tb;
        if ((unsigned)tb < SPEC_BIN || speccnt[b] > SPEC_CAP) atomicOr(flag, 1u);
    }
    __syncthreads();
    const unsigned tb = stb;
    unsigned ns = speccnt[b]; if (ns > SPEC_CAP) ns = SPEC_CAP;
    const unsigned long long* sb = spec + (size_t)b * SPEC_CAP;
    unsigned long long* cb = cand + (size_t)b * CAP;
    for (unsigned i = tid; i < ns; i += 256) {
        unsigned long long v = sb[i];
        if ((unsigned)(v >> 52) >= tb) {          // key>>20
            unsigned p = atomicAdd(&lcnt, 1u);    // LDS counter
            if (p < CAP) cb[p] = v;
        }
    }
    __syncthreads();
    if (tid == 0) cnt[b] = lcnt < CAP ? lcnt : CAP;
}

// Exactness repair: full rescan collect if speculation missed (early-exit
// ~2us in the normal case; does the same check every call).
__global__ __launch_bounds__(512) void repair_kernel(const float* __restrict__ cls,
                                                     const unsigned* __restrict__ tbin,
                                                     const unsigned* __restrict__ flag,
                                                     unsigned* __restrict__ cntR,
                                                     unsigned long long* __restrict__ candR) {
    if (*flag == 0u) return;
    __shared__ unsigned long long stg[STAGE_CAP];
    __shared__ unsigned lcnt, gbase;
    const int b = blockIdx.x / NBLK_H;
    const int blk = blockIdx.x % NBLK_H;
    if (threadIdx.x == 0) lcnt = 0;
    __syncthreads();
    const unsigned tb = tbin[b];
    const float4* src = (const float4*)(cls + (size_t)b * NEL);
    unsigned long long* cb = candR + (size_t)b * CAP;
    for (int i = blk * 512 + threadIdx.x; i < NVEC; i += NBLK_H * 512) {
        float4 v = src[i];
        float xs[4] = {v.x, v.y, v.z, v.w};
#pragma unroll
        for (int j = 0; j < 4; ++j) {
            unsigned k = f2key(xs[j]);
            if ((k >> 20) >= tb) {
                unsigned long long pack = ((unsigned long long)k << 32) |
                                          (unsigned long long)(0xFFFFFFFFu - (unsigned)(i * 4 + j));
                unsigned p = atomicAdd(&lcnt, 1u);
                if (p < STAGE_CAP) stg[p] = pack;
                else {
                    unsigned pos = atomicAdd(&cntR[b], 1u);
                    if (pos < CAP) cb[pos] = pack;
                }
            }
        }
    }
    __syncthreads();
    unsigned n = lcnt < STAGE_CAP ? lcnt : STAGE_CAP;
    if (threadIdx.x == 0) gbase = atomicAdd(&cntR[b], n);
    __syncthreads();
    for (unsigned t = threadIdx.x; t < n; t += 512) {
        unsigned pos = gbase + t;
        if (pos < CAP) cb[pos] = stg[t];
    }
}

// Wide top-1000 selection: 16 blocks/batch x 128 thr (2 waves -> half the
// per-CU LDS-broadcast chain of the 256-thr version). Ranks are a
// permutation -> scatter by rank, no conflicts.
__global__ __launch_bounds__(SELTHR) void select_kernel(const float* __restrict__ quality,
                                                        const unsigned long long* __restrict__ cand,
                                                        const unsigned* __restrict__ cnt,
                                                        const unsigned long long* __restrict__ candR,
                                                        const unsigned* __restrict__ cntR,
                                                        const unsigned* __restrict__ flag,
                                                        unsigned long long* __restrict__ top_rr,
                                                        float* __restrict__ top_s) {
    __shared__ unsigned long long arr[CAP];
    const int b = blockIdx.x / SELBLK;
    const int bk = blockIdx.x % SELBLK;
    const int tid = threadIdx.x;
    const bool rep = (*flag != 0u);
    int n = (int)(rep ? cntR[b] : cnt[b]);
    if (n > CAP) n = CAP;
    if (bk * SELTHR >= n) return;     // uniform per block, before any barrier
    const unsigned long long* src = (rep ? candR : cand) + (size_t)b * CAP;
    for (int i = tid; i < n; i += SELTHR) arr[i] = src[i];
    __syncthreads();

    const int ci = bk * SELTHR + tid;
    if (ci < n) {
        const unsigned long long m = arr[ci];
        int r = 0, j = 0;
        for (; j + 16 <= n; j += 16) {
            unsigned long long v0 = arr[j+0],  v1 = arr[j+1],  v2 = arr[j+2],  v3 = arr[j+3];
            unsigned long long v4 = arr[j+4],  v5 = arr[j+5],  v6 = arr[j+6],  v7 = arr[j+7];
            unsigned long long v8 = arr[j+8],  v9 = arr[j+9],  vA = arr[j+10], vB = arr[j+11];
            unsigned long long vC = arr[j+12], vD = arr[j+13], vE = arr[j+14], vF = arr[j+15];
            r += (v0 > m) + (v1 > m) + (v2 > m) + (v3 > m)
               + (v4 > m) + (v5 > m) + (v6 > m) + (v7 > m)
               + (v8 > m) + (v9 > m) + (vA > m) + (vB > m)
               + (vC > m) + (vD > m) + (vE > m) + (vF > m);
        }
        for (; j < n; ++j) r += (arr[j] > m);

        if (r < TOPK) {
            unsigned key = (unsigned)(m >> 32);
            unsigned idx = 0xFFFFFFFFu - (unsigned)(m & 0xFFFFFFFFu);
            unsigned q = idx / 10u;
            float logit = key2f(key);
            float s = (float)(1.0 / (1.0 + exp(-(double)logit)));   // correctly-rounded f32 sigmoid
            float ctr = quality[((size_t)b * NQ + q) * 2];
            float cs = (float)(1.0 / (1.0 + exp(-(double)ctr)));
            float rr = s * cs;                                      // f32 multiply, matches ref
            top_rr[(size_t)b * 1024 + r] = ((unsigned long long)__float_as_uint(rr) << 32) |
                                           (unsigned long long)(0xFFFFFFFFu - idx);  // rr desc, idx asc
            top_s[(size_t)b * 1024 + r] = s;
        }
    }
}

// Wide rerank sort + decode: 16 blocks/batch x 64 thr (1 wave).
__global__ __launch_bounds__(64) void sortdecode_kernel(const float* __restrict__ box_preds,
                                                        const unsigned long long* __restrict__ top_rr,
                                                        const float* __restrict__ top_s,
                                                        float* __restrict__ out) {
    __shared__ unsigned long long rr2[TOPK];
    const int b = blockIdx.x / SRTBLK;
    const int bk = blockIdx.x % SRTBLK;
    const int tid = threadIdx.x;
    for (int i = tid; i < TOPK; i += 64)
        rr2[i] = top_rr[(size_t)b * 1024 + i];
    __syncthreads();

    const int p = bk * 64 + tid;      // this thread's selection-rank entry
    if (p < TOPK) {
        const unsigned long long mine = rr2[p];
        int r = 0, j = 0;
        for (; j + 16 <= TOPK; j += 16) {
            unsigned long long v0 = rr2[j+0],  v1 = rr2[j+1],  v2 = rr2[j+2],  v3 = rr2[j+3];
            unsigned long long v4 = rr2[j+4],  v5 = rr2[j+5],  v6 = rr2[j+6],  v7 = rr2[j+7];
            unsigned long long v8 = rr2[j+8],  v9 = rr2[j+9],  vA = rr2[j+10], vB = rr2[j+11];
            unsigned long long vC = rr2[j+12], vD = rr2[j+13], vE = rr2[j+14], vF = rr2[j+15];
            r += (v0 > mine) + (v1 > mine) + (v2 > mine) + (v3 > mine)
               + (v4 > mine) + (v5 > mine) + (v6 > mine) + (v7 > mine)
               + (v8 > mine) + (v9 > mine) + (vA > mine) + (vB > mine)
               + (vC > mine) + (vD > mine) + (vE > mine) + (vF > mine);
        }
        for (; j < TOPK; ++j) r += (rr2[j] > mine);

        unsigned idx = 0xFFFFFFFFu - (unsigned)(mine & 0xFFFFFFFFu);
        float rr = __uint_as_float((unsigned)(mine >> 32));   // rr > 0: raw bits
        unsigned q = idx / 10u;
        unsigned c = idx - q * 10u;
        float s = top_s[(size_t)b * 1024 + p];

        const size_t row = (size_t)b * TOPK + (size_t)r;
        out[(size_t)BATCHES * TOPK * 10 + row] = rr;        // final_scores
        out[(size_t)BATCHES * TOPK * 11 + row] = (float)c;  // labels_3d
        out[(size_t)BATCHES * TOPK * 12 + row] = s;         // cls_scores_origin
        const float* bp = box_preds + ((size_t)b * NQ + q) * 10;
        float* ob = out + row * 10;
        ob[0] = bp[0];
        ob[1] = bp[1];
        ob[2] = bp[2];
        ob[3] = expf(bp[3]);
        ob[4] = expf(bp[4]);
        ob[5] = expf(bp[5]);
        ob[6] = atan2f(bp[6], bp[7]);
        ob[7] = bp[8];
        ob[8] = bp[9];
        ob[9] = 0.0f;
    }
}

extern "C" void kernel_launch(void* const* d_in, const int* in_sizes, int n_in,
                              void* d_out, int out_size, void* d_ws, size_t ws_size,
                              hipStream_t stream) {
    (void)in_sizes; (void)n_in; (void)out_size; (void)ws_size;
    const float* cls = (const float*)d_in[0];
    const float* box = (const float*)d_in[1];
    const float* qual = (const float*)d_in[2];
    float* out = (float*)d_out;
    char* ws = (char*)d_ws;
    // ws layout (bytes):
    //   0      counters: cnt[8]@0, speccnt[8]@32, tbin[8]@64, cntR[8]@96, flag@128 (zeroed, 256B)
    //   256    cand   8*2048 u64 = 131072
    //   131328 candR  8*2048 u64 = 131072
    //   262400 top_rr 8*1024 u64 = 65536
    //   327936 top_s  8*1024 f32 = 32768
    //   360704 spec   8*8192 u64 = 524288
    //   884992 phist  8*32*4096 u32 = 4194304   (fully overwritten, no zeroing)
    unsigned* cnt = (unsigned*)ws;
    unsigned* speccnt = (unsigned*)(ws + 32);
    unsigned* tbin = (unsigned*)(ws + 64);
    unsigned* cntR = (unsigned*)(ws + 96);
    unsigned* flag = (unsigned*)(ws + 128);
    unsigned long long* cand = (unsigned long long*)(ws + 256);
    unsigned long long* candR = (unsigned long long*)(ws + 131328);
    unsigned long long* top_rr = (unsigned long long*)(ws + 262400);
    float* top_s = (float*)(ws + 327936);
    unsigned long long* spec = (unsigned long long*)(ws + 360704);
    unsigned* phist = (unsigned*)(ws + 884992);

    hipMemsetAsync(d_ws, 0, 256, stream);  // counters only
    histspec_kernel<<<BATCHES * NBLK_H, 512, 0, stream>>>(cls, phist, speccnt, spec);
    threshcompact_kernel<<<BATCHES, 256, 0, stream>>>(phist, speccnt, spec, tbin, cnt, cand, flag);
    repair_kernel<<<BATCHES * NBLK_H, 512, 0, stream>>>(cls, tbin, flag, cntR, candR);
    select_kernel<<<BATCHES * SELBLK, SELTHR, 0, stream>>>(qual, cand, cnt, candR, cntR, flag, top_rr, top_s);
    sortdecode_kernel<<<BATCHES * SRTBLK, 64, 0, stream>>>(box, top_rr, top_s, out);
}

// Round 7
// 154.326 us; speedup vs baseline: 1.0415x; 1.0415x over previous
//
#include <hip/hip_runtime.h>
#include <stdint.h>
#include <math.h>

// SparseBox3DDecoderLite: B=8, Q=100000, C=10, K=1000
// R4 structure (proven 147.8us) + single-wave wide rank-count kernels.
// Pipeline: 12-bit-key histogram radix-select -> candidate collect (block-
// aggregated atomics) -> wide 1-wave rank-count select (256 blocks) ->
// wide 1-wave rerank sort + decode (128 blocks).
// Outputs (float32, concatenated): boxes[8,1000,10], final_scores[8,1000],
// labels[8,1000], raw_scores[8,1000]  => 104000 floats.

#define BATCHES 8
#define NQ 100000
#define NEL 1000000   // Q*C per batch
#define NVEC 250000   // NEL/4
#define TOPK 1000
#define NBINS 4096
#define CAP 2048
#define NBLK 64       // blocks per batch for scan kernels
#define NTHR 512
#define STAGE_CAP 512 // per-block candidate staging (expected ~21/block)
#define SELBLK 32     // blocks per batch, select (32*64 == CAP)
#define SELTHR 64     // single wave
#define SRTBLK 16     // blocks per batch, sortdecode (16*64 >= TOPK)

__device__ __forceinline__ unsigned f2key(float f) {
    unsigned b = __float_as_uint(f);
    return b ^ ((b & 0x80000000u) ? 0xFFFFFFFFu : 0x80000000u);
}
__device__ __forceinline__ float key2f(unsigned k) {
    unsigned b = (k & 0x80000000u) ? (k ^ 0x80000000u) : ~k;
    return __uint_as_float(b);
}

__global__ __launch_bounds__(NTHR) void hist_kernel(const float* __restrict__ cls,
                                                    unsigned* __restrict__ ghist) {
    __shared__ unsigned lh[NBINS];
    const int b = blockIdx.x / NBLK;
    const int blk = blockIdx.x % NBLK;
    for (int i = threadIdx.x; i < NBINS; i += NTHR) lh[i] = 0;
    __syncthreads();
    const float4* src = (const float4*)(cls + (size_t)b * NEL);
    for (int i = blk * NTHR + threadIdx.x; i < NVEC; i += NBLK * NTHR) {
        float4 v = src[i];
        atomicAdd(&lh[f2key(v.x) >> 20], 1u);
        atomicAdd(&lh[f2key(v.y) >> 20], 1u);
        atomicAdd(&lh[f2key(v.z) >> 20], 1u);
        atomicAdd(&lh[f2key(v.w) >> 20], 1u);
    }
    __syncthreads();
    unsigned* gh = ghist + (size_t)b * NBINS;
    for (int i = threadIdx.x; i < NBINS; i += NTHR) {
        unsigned v = lh[i];
        if (v) atomicAdd(&gh[i], v);   // distinct addresses -> pipelined fine
    }
}

__global__ __launch_bounds__(256) void thresh_kernel(const unsigned* __restrict__ ghist,
                                                     unsigned* __restrict__ tbin) {
    __shared__ unsigned sh[NBINS];
    __shared__ unsigned coarse[256];
    const int b = blockIdx.x;
    for (int i = threadIdx.x; i < NBINS; i += 256) sh[i] = ghist[(size_t)b * NBINS + i];
    __syncthreads();
    unsigned s = 0;
    const int base = threadIdx.x * 16;
#pragma unroll
    for (int j = 0; j < 16; ++j) s += sh[base + j];
    coarse[threadIdx.x] = s;
    __syncthreads();
    if (threadIdx.x == 0) {
        unsigned acc = 0;
        int tb = 0;
        for (int c = 255; c >= 0; --c) {
            if (acc + coarse[c] >= (unsigned)TOPK) {
                for (int bin = c * 16 + 15; bin >= c * 16; --bin) {
                    acc += sh[bin];
                    if (acc >= (unsigned)TOPK) { tb = bin; break; }
                }
                break;
            }
            acc += coarse[c];
        }
        tbin[b] = (unsigned)tb;
    }
}

// Block-aggregated candidate collection: LDS staging + ONE global
// atomicAdd(cnt[b]) per block.
__global__ __launch_bounds__(NTHR) void collect_kernel(const float* __restrict__ cls,
                                                       const unsigned* __restrict__ tbin,
                                                       unsigned* __restrict__ cnt,
                                                       unsigned long long* __restrict__ cand) {
    __shared__ unsigned long long stage[STAGE_CAP];
    __shared__ unsigned lcnt;
    __shared__ unsigned gbase;
    const int b = blockIdx.x / NBLK;
    const int blk = blockIdx.x % NBLK;
    if (threadIdx.x == 0) lcnt = 0;
    __syncthreads();
    const unsigned tb = tbin[b];
    const float4* src = (const float4*)(cls + (size_t)b * NEL);
    unsigned long long* cb = cand + (size_t)b * CAP;
    for (int i = blk * NTHR + threadIdx.x; i < NVEC; i += NBLK * NTHR) {
        float4 v = src[i];
        float xs[4] = {v.x, v.y, v.z, v.w};
#pragma unroll
        for (int j = 0; j < 4; ++j) {
            unsigned k = f2key(xs[j]);
            if ((k >> 20) >= tb) {
                unsigned idx = (unsigned)(i * 4 + j);
                unsigned long long pack = ((unsigned long long)k << 32) |
                                          (unsigned long long)(0xFFFFFFFFu - idx);
                unsigned p = atomicAdd(&lcnt, 1u);
                if (p < STAGE_CAP) {
                    stage[p] = pack;
                } else {                       // exactness fallback (never on this data)
                    unsigned pos = atomicAdd(&cnt[b], 1u);
                    if (pos < CAP) cb[pos] = pack;
                }
            }
        }
    }
    __syncthreads();
    unsigned n = lcnt < STAGE_CAP ? lcnt : STAGE_CAP;
    if (threadIdx.x == 0) gbase = atomicAdd(&cnt[b], n);
    __syncthreads();
    for (unsigned t = threadIdx.x; t < n; t += NTHR) {
        unsigned pos = gbase + t;
        if (pos < CAP) cb[pos] = stage[t];
    }
}

// Wide top-1000 selection: 32 blocks/batch x 64 thr (ONE wave per block, one
// block per CU -> per-CU LDS broadcast chain is n (~1350), not waves*n).
// Ranks are a permutation -> scatter by rank, no conflicts.
__global__ __launch_bounds__(SELTHR) void select_kernel(const float* __restrict__ quality,
                                                        const unsigned long long* __restrict__ cand,
                                                        const unsigned* __restrict__ cnt,
                                                        unsigned long long* __restrict__ top_rr,
                                                        float* __restrict__ top_s) {
    __shared__ unsigned long long arr[CAP];
    const int b = blockIdx.x / SELBLK;
    const int bk = blockIdx.x % SELBLK;
    const int tid = threadIdx.x;
    int n = (int)cnt[b];
    if (n > CAP) n = CAP;
    if (bk * SELTHR >= n) return;     // uniform per block (no barrier yet)
    const unsigned long long* src = cand + (size_t)b * CAP;
    for (int i = tid; i < n; i += SELTHR) arr[i] = src[i];
    __syncthreads();

    const int ci = bk * SELTHR + tid;
    if (ci < n) {
        const unsigned long long m = arr[ci];
        int r = 0, j = 0;
        for (; j + 16 <= n; j += 16) {
            unsigned long long v0 = arr[j+0],  v1 = arr[j+1],  v2 = arr[j+2],  v3 = arr[j+3];
            unsigned long long v4 = arr[j+4],  v5 = arr[j+5],  v6 = arr[j+6],  v7 = arr[j+7];
            unsigned long long v8 = arr[j+8],  v9 = arr[j+9],  vA = arr[j+10], vB = arr[j+11];
            unsigned long long vC = arr[j+12], vD = arr[j+13], vE = arr[j+14], vF = arr[j+15];
            r += (v0 > m) + (v1 > m) + (v2 > m) + (v3 > m)
               + (v4 > m) + (v5 > m) + (v6 > m) + (v7 > m)
               + (v8 > m) + (v9 > m) + (vA > m) + (vB > m)
               + (vC > m) + (vD > m) + (vE > m) + (vF > m);
        }
        for (; j < n; ++j) r += (arr[j] > m);

        if (r < TOPK) {
            unsigned key = (unsigned)(m >> 32);
            unsigned idx = 0xFFFFFFFFu - (unsigned)(m & 0xFFFFFFFFu);
            unsigned q = idx / 10u;
            float logit = key2f(key);
            float s = (float)(1.0 / (1.0 + exp(-(double)logit)));   // correctly-rounded f32 sigmoid
            float ctr = quality[((size_t)b * NQ + q) * 2];
            float cs = (float)(1.0 / (1.0 + exp(-(double)ctr)));
            float rr = s * cs;                                      // f32 multiply, matches ref
            top_rr[(size_t)b * 1024 + r] = ((unsigned long long)__float_as_uint(rr) << 32) |
                                           (unsigned long long)(0xFFFFFFFFu - idx);  // rr desc, idx asc
            top_s[(size_t)b * 1024 + r] = s;
        }
    }
}

// Wide rerank sort + decode: 16 blocks/batch x 64 thr (one wave per block).
__global__ __launch_bounds__(64) void sortdecode_kernel(const float* __restrict__ box_preds,
                                                        const unsigned long long* __restrict__ top_rr,
                                                        const float* __restrict__ top_s,
                                                        float* __restrict__ out) {
    __shared__ unsigned long long rr2[TOPK];
    const int b = blockIdx.x / SRTBLK;
    const int bk = blockIdx.x % SRTBLK;
    const int tid = threadIdx.x;
    for (int i = tid; i < TOPK; i += 64)
        rr2[i] = top_rr[(size_t)b * 1024 + i];
    __syncthreads();

    const int p = bk * 64 + tid;      // this thread's selection-rank entry
    if (p < TOPK) {
        const unsigned long long mine = rr2[p];
        int r = 0, j = 0;
        for (; j + 16 <= TOPK; j += 16) {
            unsigned long long v0 = rr2[j+0],  v1 = rr2[j+1],  v2 = rr2[j+2],  v3 = rr2[j+3];
            unsigned long long v4 = rr2[j+4],  v5 = rr2[j+5],  v6 = rr2[j+6],  v7 = rr2[j+7];
            unsigned long long v8 = rr2[j+8],  v9 = rr2[j+9],  vA = rr2[j+10], vB = rr2[j+11];
            unsigned long long vC = rr2[j+12], vD = rr2[j+13], vE = rr2[j+14], vF = rr2[j+15];
            r += (v0 > mine) + (v1 > mine) + (v2 > mine) + (v3 > mine)
               + (v4 > mine) + (v5 > mine) + (v6 > mine) + (v7 > mine)
               + (v8 > mine) + (v9 > mine) + (vA > mine) + (vB > mine)
               + (vC > mine) + (vD > mine) + (vE > mine) + (vF > mine);
        }
        for (; j < TOPK; ++j) r += (rr2[j] > mine);

        unsigned idx = 0xFFFFFFFFu - (unsigned)(mine & 0xFFFFFFFFu);
        float rr = __uint_as_float((unsigned)(mine >> 32));   // rr > 0: raw bits
        unsigned q = idx / 10u;
        unsigned c = idx - q * 10u;
        float s = top_s[(size_t)b * 1024 + p];

        const size_t row = (size_t)b * TOPK + (size_t)r;
        out[(size_t)BATCHES * TOPK * 10 + row] = rr;        // final_scores
        out[(size_t)BATCHES * TOPK * 11 + row] = (float)c;  // labels_3d
        out[(size_t)BATCHES * TOPK * 12 + row] = s;         // cls_scores_origin
        const float* bp = box_preds + ((size_t)b * NQ + q) * 10;
        float* ob = out + row * 10;
        ob[0] = bp[0];
        ob[1] = bp[1];
        ob[2] = bp[2];
        ob[3] = expf(bp[3]);
        ob[4] = expf(bp[4]);
        ob[5] = expf(bp[5]);
        ob[6] = atan2f(bp[6], bp[7]);
        ob[7] = bp[8];
        ob[8] = bp[9];
        ob[9] = 0.0f;
    }
}

extern "C" void kernel_launch(void* const* d_in, const int* in_sizes, int n_in,
                              void* d_out, int out_size, void* d_ws, size_t ws_size,
                              hipStream_t stream) {
    (void)in_sizes; (void)n_in; (void)out_size; (void)ws_size;
    const float* cls = (const float*)d_in[0];
    const float* box = (const float*)d_in[1];
    const float* qual = (const float*)d_in[2];
    float* out = (float*)d_out;
    char* ws = (char*)d_ws;
    // ws layout: ghist[8*4096 u32]=131072B | cnt[8 u32]=32B | tbin[8 u32]=32B |
    //            cand[8*2048 u64]=131072B | top_rr[8*1024 u64]=65536B | top_s[8*1024 f32]=32768B
    unsigned* ghist = (unsigned*)ws;
    unsigned* cnt = (unsigned*)(ws + 131072);
    unsigned* tbin = (unsigned*)(ws + 131072 + 32);
    unsigned long long* cand = (unsigned long long*)(ws + 131072 + 64);
    unsigned long long* top_rr = (unsigned long long*)(ws + 131072 + 64 + 131072);
    float* top_s = (float*)(ws + 131072 + 64 + 131072 + 65536);

    hipMemsetAsync(d_ws, 0, 131072 + 32, stream);  // zero ghist + cnt
    hist_kernel<<<BATCHES * NBLK, NTHR, 0, stream>>>(cls, ghist);
    thresh_kernel<<<BATCHES, 256, 0, stream>>>(ghist, tbin);
    collect_kernel<<<BATCHES * NBLK, NTHR, 0, stream>>>(cls, tbin, cnt, cand);
    select_kernel<<<BATCHES * SELBLK, SELTHR, 0, stream>>>(qual, cand, cnt, top_rr, top_s);
    sortdecode_kernel<<<BATCHES * SRTBLK, 64, 0, stream>>>(box, top_rr, top_s, out);
}

// Round 10
// 152.138 us; speedup vs baseline: 1.0565x; 1.0144x over previous
//
#include <hip/hip_runtime.h>
#include <stdint.h>
#include <math.h>

// SparseBox3DDecoderLite: B=8, Q=100000, C=10, K=1000
// ONE 32MB pass: hist (LDS + global-atomic merge, R4-proven shape) fused with
// speculative candidate staging (bin>=3075 ~ logit>=2.75, ~2980/batch) ->
// threshcompact: exact threshold bin from 16KB ghist + filter spec list into
// cand (in-kernel full-rescan fallback for arbitrary data; never taken here)
// -> wide 1-wave rank-count select -> wide 1-wave rerank sort + decode.
// Outputs (float32, concatenated): boxes[8,1000,10], final_scores[8,1000],
// labels[8,1000], raw_scores[8,1000]  => 104000 floats.

#define BATCHES 8
#define NQ 100000
#define NEL 1000000   // Q*C per batch
#define NVEC 250000   // NEL/4
#define TOPK 1000
#define NBINS 4096
#define CAP 2048
#define NBLK 64       // blocks per batch, histspec
#define NTHR 512
#define STAGE_CAP 512 // per-block spec staging (expected ~47/block)
#define SPEC_CAP 8192 // per-batch spec list (expected ~2980)
#define SPEC_BIN 3075u   // f2key(2.75f)>>20; exact tb on this data is 3076
#define SELBLK 32     // blocks per batch, select (32*64 == CAP)
#define SELTHR 64     // single wave
#define SRTBLK 16     // blocks per batch, sortdecode (16*64 >= TOPK)

__device__ __forceinline__ unsigned f2key(float f) {
    unsigned b = __float_as_uint(f);
    return b ^ ((b & 0x80000000u) ? 0xFFFFFFFFu : 0x80000000u);
}
__device__ __forceinline__ float key2f(unsigned k) {
    unsigned b = (k & 0x80000000u) ? (k ^ 0x80000000u) : ~k;
    return __uint_as_float(b);
}

// Histogram (R4-proven shape) + speculative staging of bin>=SPEC_BIN.
__global__ __launch_bounds__(NTHR) void histspec_kernel(const float* __restrict__ cls,
                                                        unsigned* __restrict__ ghist,
                                                        unsigned* __restrict__ speccnt,
                                                        unsigned long long* __restrict__ spec) {
    __shared__ unsigned lh[NBINS];
    __shared__ unsigned long long stg[STAGE_CAP];
    __shared__ unsigned lcnt, gbase;
    const int b = blockIdx.x / NBLK;
    const int blk = blockIdx.x % NBLK;
    for (int i = threadIdx.x; i < NBINS; i += NTHR) lh[i] = 0;
    if (threadIdx.x == 0) lcnt = 0;
    __syncthreads();
    const float4* src = (const float4*)(cls + (size_t)b * NEL);
    unsigned long long* sb = spec + (size_t)b * SPEC_CAP;
    for (int i = blk * NTHR + threadIdx.x; i < NVEC; i += NBLK * NTHR) {
        float4 v = src[i];
        float xs[4] = {v.x, v.y, v.z, v.w};
#pragma unroll
        for (int j = 0; j < 4; ++j) {
            unsigned k = f2key(xs[j]);
            unsigned bin = k >> 20;
            atomicAdd(&lh[bin], 1u);
            if (bin >= SPEC_BIN) {
                unsigned long long pack = ((unsigned long long)k << 32) |
                                          (unsigned long long)(0xFFFFFFFFu - (unsigned)(i * 4 + j));
                unsigned p = atomicAdd(&lcnt, 1u);
                if (p < STAGE_CAP) stg[p] = pack;
                else {  // exactness fallback (10x headroom; never on this data)
                    unsigned pos = atomicAdd(&speccnt[b], 1u);
                    if (pos < SPEC_CAP) sb[pos] = pack;
                }
            }
        }
    }
    __syncthreads();
    unsigned* gh = ghist + (size_t)b * NBINS;
    for (int i = threadIdx.x; i < NBINS; i += NTHR) {
        unsigned v = lh[i];
        if (v) atomicAdd(&gh[i], v);   // distinct addresses -> pipelined fine
    }
    unsigned n = lcnt < STAGE_CAP ? lcnt : STAGE_CAP;
    if (threadIdx.x == 0) gbase = atomicAdd(&speccnt[b], n);
    __syncthreads();
    for (unsigned t = threadIdx.x; t < n; t += NTHR) {
        unsigned pos = gbase + t;
        if (pos < SPEC_CAP) sb[pos] = stg[t];
    }
}

// Per batch (1 block): exact threshold bin from ghist (16KB), then filter the
// spec list (~24KB) into cand. Fallback: full 32MB/8 rescan if speculation
// can't cover the threshold (arbitrary-data correctness; never taken here).
__global__ __launch_bounds__(256) void threshcompact_kernel(const unsigned* __restrict__ ghist,
                                                            const unsigned* __restrict__ speccnt,
                                                            const unsigned long long* __restrict__ spec,
                                                            const float* __restrict__ cls,
                                                            unsigned* __restrict__ cnt,
                                                            unsigned long long* __restrict__ cand) {
    __shared__ unsigned sh[NBINS];
    __shared__ unsigned coarse[256];
    __shared__ unsigned stb, lcnt;
    const int b = blockIdx.x;
    const int tid = threadIdx.x;
    for (int i = tid; i < NBINS; i += 256) sh[i] = ghist[(size_t)b * NBINS + i];
    if (tid == 0) lcnt = 0;
    __syncthreads();
    unsigned s = 0;
    const int base = tid * 16;
#pragma unroll
    for (int j = 0; j < 16; ++j) s += sh[base + j];
    coarse[tid] = s;
    __syncthreads();
    if (tid == 0) {
        unsigned acc = 0;
        int tb = 0;
        for (int c = 255; c >= 0; --c) {
            if (acc + coarse[c] >= (unsigned)TOPK) {
                for (int bin = c * 16 + 15; bin >= c * 16; --bin) {
                    acc += sh[bin];
                    if (acc >= (unsigned)TOPK) { tb = bin; break; }
                }
                break;
            }
            acc += coarse[c];
        }
        stb = (unsigned)tb;
    }
    __syncthreads();
    const unsigned tb = stb;
    const unsigned nsr = speccnt[b];
    unsigned long long* cb = cand + (size_t)b * CAP;
    if (tb >= SPEC_BIN && nsr <= SPEC_CAP) {
        // normal path: filter spec list through exact threshold
        const unsigned long long* sb = spec + (size_t)b * SPEC_CAP;
        for (unsigned i = tid; i < nsr; i += 256) {
            unsigned long long v = sb[i];
            if ((unsigned)(v >> 52) >= tb) {          // key>>20
                unsigned p = atomicAdd(&lcnt, 1u);
                if (p < CAP) cb[p] = v;
            }
        }
    } else {
        // fallback: full rescan of this batch (slow; correctness-only path)
        const float4* src = (const float4*)(cls + (size_t)b * NEL);
        for (int i = tid; i < NVEC; i += 256) {
            float4 v = src[i];
            float xs[4] = {v.x, v.y, v.z, v.w};
#pragma unroll
            for (int j = 0; j < 4; ++j) {
                unsigned k = f2key(xs[j]);
                if ((k >> 20) >= tb) {
                    unsigned long long pack = ((unsigned long long)k << 32) |
                                              (unsigned long long)(0xFFFFFFFFu - (unsigned)(i * 4 + j));
                    unsigned p = atomicAdd(&lcnt, 1u);
                    if (p < CAP) cb[p] = pack;
                }
            }
        }
    }
    __syncthreads();
    if (tid == 0) cnt[b] = lcnt < CAP ? lcnt : CAP;
}

// Wide top-1000 selection: 32 blocks/batch x 64 thr (one wave per block).
// Ranks are a permutation -> scatter by rank, no conflicts.
__global__ __launch_bounds__(SELTHR) void select_kernel(const float* __restrict__ quality,
                                                        const unsigned long long* __restrict__ cand,
                                                        const unsigned* __restrict__ cnt,
                                                        unsigned long long* __restrict__ top_rr,
                                                        float* __restrict__ top_s) {
    __shared__ unsigned long long arr[CAP];
    const int b = blockIdx.x / SELBLK;
    const int bk = blockIdx.x % SELBLK;
    const int tid = threadIdx.x;
    int n = (int)cnt[b];
    if (n > CAP) n = CAP;
    if (bk * SELTHR >= n) return;     // uniform per block (no barrier yet)
    const unsigned long long* src = cand + (size_t)b * CAP;
    for (int i = tid; i < n; i += SELTHR) arr[i] = src[i];
    __syncthreads();

    const int ci = bk * SELTHR + tid;
    if (ci < n) {
        const unsigned long long m = arr[ci];
        int r = 0, j = 0;
        for (; j + 16 <= n; j += 16) {
            unsigned long long v0 = arr[j+0],  v1 = arr[j+1],  v2 = arr[j+2],  v3 = arr[j+3];
            unsigned long long v4 = arr[j+4],  v5 = arr[j+5],  v6 = arr[j+6],  v7 = arr[j+7];
            unsigned long long v8 = arr[j+8],  v9 = arr[j+9],  vA = arr[j+10], vB = arr[j+11];
            unsigned long long vC = arr[j+12], vD = arr[j+13], vE = arr[j+14], vF = arr[j+15];
            r += (v0 > m) + (v1 > m) + (v2 > m) + (v3 > m)
               + (v4 > m) + (v5 > m) + (v6 > m) + (v7 > m)
               + (v8 > m) + (v9 > m) + (vA > m) + (vB > m)
               + (vC > m) + (vD > m) + (vE > m) + (vF > m);
        }
        for (; j < n; ++j) r += (arr[j] > m);

        if (r < TOPK) {
            unsigned key = (unsigned)(m >> 32);
            unsigned idx = 0xFFFFFFFFu - (unsigned)(m & 0xFFFFFFFFu);
            unsigned q = idx / 10u;
            float logit = key2f(key);
            float s = (float)(1.0 / (1.0 + exp(-(double)logit)));   // correctly-rounded f32 sigmoid
            float ctr = quality[((size_t)b * NQ + q) * 2];
            float cs = (float)(1.0 / (1.0 + exp(-(double)ctr)));
            float rr = s * cs;                                      // f32 multiply, matches ref
            top_rr[(size_t)b * 1024 + r] = ((unsigned long long)__float_as_uint(rr) << 32) |
                                           (unsigned long long)(0xFFFFFFFFu - idx);  // rr desc, idx asc
            top_s[(size_t)b * 1024 + r] = s;
        }
    }
}

// Wide rerank sort + decode: 16 blocks/batch x 64 thr (one wave per block).
__global__ __launch_bounds__(64) void sortdecode_kernel(const float* __restrict__ box_preds,
                                                        const unsigned long long* __restrict__ top_rr,
                                                        const float* __restrict__ top_s,
                                                        float* __restrict__ out) {
    __shared__ unsigned long long rr2[TOPK];
    const int b = blockIdx.x / SRTBLK;
    const int bk = blockIdx.x % SRTBLK;
    const int tid = threadIdx.x;
    for (int i = tid; i < TOPK; i += 64)
        rr2[i] = top_rr[(size_t)b * 1024 + i];
    __syncthreads();

    const int p = bk * 64 + tid;      // this thread's selection-rank entry
    if (p < TOPK) {
        const unsigned long long mine = rr2[p];
        int r = 0, j = 0;
        for (; j + 16 <= TOPK; j += 16) {
            unsigned long long v0 = rr2[j+0],  v1 = rr2[j+1],  v2 = rr2[j+2],  v3 = rr2[j+3];
            unsigned long long v4 = rr2[j+4],  v5 = rr2[j+5],  v6 = rr2[j+6],  v7 = rr2[j+7];
            unsigned long long v8 = rr2[j+8],  v9 = rr2[j+9],  vA = rr2[j+10], vB = rr2[j+11];
            unsigned long long vC = rr2[j+12], vD = rr2[j+13], vE = rr2[j+14], vF = rr2[j+15];
            r += (v0 > mine) + (v1 > mine) + (v2 > mine) + (v3 > mine)
               + (v4 > mine) + (v5 > mine) + (v6 > mine) + (v7 > mine)
               + (v8 > mine) + (v9 > mine) + (vA > mine) + (vB > mine)
               + (vC > mine) + (vD > mine) + (vE > mine) + (vF > mine);
        }
        for (; j < TOPK; ++j) r += (rr2[j] > mine);

        unsigned idx = 0xFFFFFFFFu - (unsigned)(mine & 0xFFFFFFFFu);
        float rr = __uint_as_float((unsigned)(mine >> 32));   // rr > 0: raw bits
        unsigned q = idx / 10u;
        unsigned c = idx - q * 10u;
        float s = top_s[(size_t)b * 1024 + p];

        const size_t row = (size_t)b * TOPK + (size_t)r;
        out[(size_t)BATCHES * TOPK * 10 + row] = rr;        // final_scores
        out[(size_t)BATCHES * TOPK * 11 + row] = (float)c;  // labels_3d
        out[(size_t)BATCHES * TOPK * 12 + row] = s;         // cls_scores_origin
        const float* bp = box_preds + ((size_t)b * NQ + q) * 10;
        float* ob = out + row * 10;
        ob[0] = bp[0];
        ob[1] = bp[1];
        ob[2] = bp[2];
        ob[3] = expf(bp[3]);
        ob[4] = expf(bp[4]);
        ob[5] = expf(bp[5]);
        ob[6] = atan2f(bp[6], bp[7]);
        ob[7] = bp[8];
        ob[8] = bp[9];
        ob[9] = 0.0f;
    }
}

extern "C" void kernel_launch(void* const* d_in, const int* in_sizes, int n_in,
                              void* d_out, int out_size, void* d_ws, size_t ws_size,
                              hipStream_t stream) {
    (void)in_sizes; (void)n_in; (void)out_size; (void)ws_size;
    const float* cls = (const float*)d_in[0];
    const float* box = (const float*)d_in[1];
    const float* qual = (const float*)d_in[2];
    float* out = (float*)d_out;
    char* ws = (char*)d_ws;
    // ws layout (bytes):
    //   0       ghist   8*4096 u32 = 131072   (zeroed)
    //   131072  cnt     8 u32      = 32       (zeroed)
    //   131104  speccnt 8 u32      = 32       (zeroed)
    //   131168  cand    8*2048 u64 = 131072
    //   262240  top_rr  8*1024 u64 = 65536
    //   327776  top_s   8*1024 f32 = 32768
    //   360544  spec    8*8192 u64 = 524288
    unsigned* ghist = (unsigned*)ws;
    unsigned* cnt = (unsigned*)(ws + 131072);
    unsigned* speccnt = (unsigned*)(ws + 131104);
    unsigned long long* cand = (unsigned long long*)(ws + 131168);
    unsigned long long* top_rr = (unsigned long long*)(ws + 262240);
    float* top_s = (float*)(ws + 327776);
    unsigned long long* spec = (unsigned long long*)(ws + 360544);

    hipMemsetAsync(d_ws, 0, 131136, stream);  // ghist + cnt + speccnt
    histspec_kernel<<<BATCHES * NBLK, NTHR, 0, stream>>>(cls, ghist, speccnt, spec);
    threshcompact_kernel<<<BATCHES, 256, 0, stream>>>(ghist, speccnt, spec, cls, cnt, cand);
    select_kernel<<<BATCHES * SELBLK, SELTHR, 0, stream>>>(qual, cand, cnt, top_rr, top_s);
    sortdecode_kernel<<<BATCHES * SRTBLK, 64, 0, stream>>>(box, top_rr, top_s, out);
}